// Round 6
// baseline (30704.581 us; speedup 1.0000x reference)
//
#include <hip/hip_runtime.h>
#include <cmath>

#define N 2048
#define D 512
#define N_ITERS 200
#define NEWTON_ITERS 16
#define POWER_ITERS 30
#define NBLOCKS 256

typedef unsigned short u16;
typedef __bf16 bf16x8 __attribute__((ext_vector_type(8)));
typedef float f32x4 __attribute__((ext_vector_type(4)));

__device__ __forceinline__ float wave_reduce_sum(float x) {
#pragma unroll
  for (int o = 32; o > 0; o >>= 1) x += __shfl_xor(x, o, 64);
  return x;
}

__device__ __forceinline__ u16 f2b(float f) {  // fp32 -> bf16 RNE
  unsigned int u = __float_as_uint(f);
  u = (u + 0x7FFFu + ((u >> 16) & 1u)) >> 16;
  return (u16)u;
}

__device__ __forceinline__ float b2f(unsigned int lo16) {
  return __uint_as_float((lo16 & 0xffffu) << 16);
}

// async 16B global->LDS (wave-uniform LDS base + implicit lane*16; per-lane global src)
__device__ __forceinline__ void gload16(const u16* g, u16* l) {
  __builtin_amdgcn_global_load_lds(
      (const __attribute__((address_space(1))) unsigned int*)g,
      (__attribute__((address_space(3))) unsigned int*)l, 16, 0, 0);
}

// device-scope generation barrier; safe: grid=256 blocks is fully resident for any
// packing (LDS 64KB -> <=2 blk/CU, VGPR worst case -> 1 blk/CU; capacity >= 256).
__device__ __forceinline__ void grid_barrier(unsigned int* bar) {
  __syncthreads();
  if (threadIdx.x == 0) {
    unsigned int g = __hip_atomic_load(&bar[1], __ATOMIC_RELAXED, __HIP_MEMORY_SCOPE_AGENT);
    unsigned int a = __hip_atomic_fetch_add(&bar[0], 1u, __ATOMIC_ACQ_REL, __HIP_MEMORY_SCOPE_AGENT);
    if (a + 1u == (unsigned int)NBLOCKS) {
      __hip_atomic_store(&bar[0], 0u, __ATOMIC_RELAXED, __HIP_MEMORY_SCOPE_AGENT);
      __hip_atomic_store(&bar[1], g + 1u, __ATOMIC_RELEASE, __HIP_MEMORY_SCOPE_AGENT);
    } else {
      while (__hip_atomic_load(&bar[1], __ATOMIC_ACQUIRE, __HIP_MEMORY_SCOPE_AGENT) == g) {
        __builtin_amdgcn_s_sleep(8);
      }
    }
  }
  __syncthreads();
}

// ---------------- row normalization: Y = fea1/||row||, A = fea2/||row|| ----------------
__global__ __launch_bounds__(256) void rownorm_kernel(const float* __restrict__ fea1,
                                                      const float* __restrict__ fea2,
                                                      float* __restrict__ Y,
                                                      float* __restrict__ A) {
  int b = blockIdx.x;
  int row = b & (N - 1);
  const float* src = (b < N) ? fea1 : fea2;
  float* dst = (b < N) ? Y : A;
  const float2* s2 = (const float2*)(src + (size_t)row * D);
  float2* d2 = (float2*)(dst + (size_t)row * D);
  int t = threadIdx.x;
  float2 v = s2[t];
  float ss = v.x * v.x + v.y * v.y;
  ss = wave_reduce_sum(ss);
  __shared__ float sred[4];
  int wid = t >> 6, lane = t & 63;
  if (lane == 0) sred[wid] = ss;
  __syncthreads();
  if (t == 0) sred[0] = sred[0] + sred[1] + sred[2] + sred[3];
  __syncthreads();
  float inv = 1.0f / sqrtf(sred[0]);
  d2[t] = make_float2(v.x * inv, v.y * inv);
}

// ---------------- prep: Ab = bf16(A), AbT = bf16(A)^T ----------------
__global__ __launch_bounds__(256) void prep_kernel(const float* __restrict__ A,
                                                   u16* __restrict__ Ab,
                                                   u16* __restrict__ AbT) {
  __shared__ float tile[32][33];
  int c0 = blockIdx.x * 32, r0 = blockIdx.y * 32;
  int tid = threadIdx.x;
  int r = tid >> 3, q = tid & 7;
  float4 v = *(const float4*)&A[(size_t)(r0 + r) * D + c0 + q * 4];
  tile[r][q * 4 + 0] = v.x; tile[r][q * 4 + 1] = v.y;
  tile[r][q * 4 + 2] = v.z; tile[r][q * 4 + 3] = v.w;
  ushort4 b4 = make_ushort4(f2b(v.x), f2b(v.y), f2b(v.z), f2b(v.w));
  *(ushort4*)&Ab[(size_t)(r0 + r) * D + c0 + q * 4] = b4;
  __syncthreads();
  int c = tid >> 3, qq = tid & 7;
  ushort4 t4 = make_ushort4(f2b(tile[qq * 4 + 0][c]), f2b(tile[qq * 4 + 1][c]),
                            f2b(tile[qq * 4 + 2][c]), f2b(tile[qq * 4 + 3][c]));
  *(ushort4*)&AbT[(size_t)(c0 + c) * N + r0 + qq * 4] = t4;
}

// ---------------- init Zb = Xb = bf16(1/N), v = 1/N, zero barrier ----------------
__global__ __launch_bounds__(256) void fill_init(u16* __restrict__ Zb, u16* __restrict__ Xb,
                                                 float* __restrict__ v,
                                                 unsigned int* __restrict__ bar) {
  const float c = 1.0f / (float)N;
  const unsigned int cw = (unsigned int)f2b(c);
  const unsigned int pp = cw | (cw << 16);
  size_t i = (size_t)blockIdx.x * blockDim.x + threadIdx.x;  // 0 .. N*N/8-1
  uint4 val = make_uint4(pp, pp, pp, pp);
  ((uint4*)Zb)[i] = val;
  ((uint4*)Xb)[i] = val;
  if (i < N) v[i] = c;
  if (i < 4) bar[i] = 0u;
}

// ---------------- power iteration (Q v = A (A^T v)), bf16 A, fixed rescale ----------
__global__ __launch_bounds__(256) void atv_kernel(const u16* __restrict__ Ab,
                                                  const float* __restrict__ v,
                                                  float* __restrict__ u) {
  __shared__ float part[4][64];
  int lane = threadIdx.x & 63, wid = threadIdx.x >> 6;
  int d = blockIdx.x * 64 + lane;
  float acc = 0.f;
  int r0 = wid * 512;
  for (int i = 0; i < 512; ++i) {
    int r = r0 + i;
    acc = fmaf(b2f(Ab[(size_t)r * D + d]), v[r], acc);
  }
  part[wid][lane] = acc;
  __syncthreads();
  if (wid == 0) u[d] = part[0][lane] + part[1][lane] + part[2][lane] + part[3][lane];
}

__global__ __launch_bounds__(256) void av_kernel(const u16* __restrict__ Ab,
                                                 const float* __restrict__ u,
                                                 float* __restrict__ w) {
  int wid = threadIdx.x >> 6, lane = threadIdx.x & 63;
  int row = blockIdx.x * 4 + wid;
  uint4 q = *(const uint4*)&Ab[(size_t)row * D + lane * 8];
  float4 u0 = *(const float4*)&u[lane * 8];
  float4 u1 = *(const float4*)&u[lane * 8 + 4];
  float acc = 0.f;
  acc = fmaf(b2f(q.x), u0.x, acc);
  acc = fmaf(b2f(q.x >> 16), u0.y, acc);
  acc = fmaf(b2f(q.y), u0.z, acc);
  acc = fmaf(b2f(q.y >> 16), u0.w, acc);
  acc = fmaf(b2f(q.z), u1.x, acc);
  acc = fmaf(b2f(q.z >> 16), u1.y, acc);
  acc = fmaf(b2f(q.w), u1.z, acc);
  acc = fmaf(b2f(q.w >> 16), u1.w, acc);
  acc = wave_reduce_sum(acc);
  if (lane == 0) w[row] = acc * 0.0625f;   // fixed 1/16 rescale keeps fp32 range
}

// lam = 16 * (v.w)/(v.v); step = 1/(2 lam + 1e-12)
__global__ __launch_bounds__(1024) void rayleigh_kernel(const float* __restrict__ v,
                                                        const float* __restrict__ w,
                                                        float* __restrict__ step) {
  int t = threadIdx.x;
  float a0 = v[t], a1 = v[t + 1024];
  float b0 = w[t], b1 = w[t + 1024];
  float s1 = a0 * b0 + a1 * b1;
  float s2 = a0 * a0 + a1 * a1;
  s1 = wave_reduce_sum(s1);
  s2 = wave_reduce_sum(s2);
  __shared__ float r1[16], r2[16];
  int wid = t >> 6, lane = t & 63;
  if (lane == 0) { r1[wid] = s1; r2[wid] = s2; }
  __syncthreads();
  if (t == 0) {
    float t1 = 0.f, t2 = 0.f;
#pragma unroll
    for (int i = 0; i < 16; ++i) { t1 += r1[i]; t2 += r2[i]; }
    float lam = 16.0f * t1 / t2;
    step[0] = 1.0f / (2.0f * lam + 1e-12f);
  }
}

// ================= persistent FISTA kernel: 256 blocks x 512 thr =================
// Phase g1: T = Z@A - Y (64x64 tiles, 8 waves 2x4, BK=128, dbuf, XOR swizzle)
// Phase g2: G = T@A^T (128x128 tiles, 8 waves 2x4, BK=64, dbuf, XOR swizzle)
// Phase prox: per-row capped-simplex projection + momentum (1 row/wave)

template <int FOUT>
__device__ __forceinline__ void phase_g1(u16* lds, const u16* __restrict__ Am,
                                         const u16* __restrict__ Bm,
                                         const float* __restrict__ Y,
                                         u16* __restrict__ outb, float* __restrict__ outf,
                                         int bid, int tid) {
  const int lane = tid & 63, wid = tid >> 6;
  const int row0 = (bid >> 3) * 64, col0 = (bid & 7) * 64;
  const int wr = (wid >> 2) * 32, wc = (wid & 3) * 16;
  const int fr = lane & 15, h = lane >> 4;
  const int grow = lane >> 4, gslot = lane & 15;
  f32x4 acc[2] = {};

#define G1S(BUF, T)                                                              \
  {                                                                              \
    const int k0 = (T) * 128;                                                    \
    _Pragma("unroll") for (int q = 0; q < 2; ++q) {                              \
      const int m = wid * 2 + q;                                                 \
      const int r = m * 4 + grow;                                                \
      const int kl = (gslot ^ (r & 15)) * 8;                                     \
      gload16(&Am[(size_t)(row0 + r) * 2048 + k0 + kl], &lds[(BUF)*16384 + m*512]);        \
      gload16(&Bm[(size_t)(col0 + r) * 2048 + k0 + kl], &lds[(BUF)*16384 + 8192 + m*512]); \
    }                                                                            \
  }

  G1S(0, 0);
  __syncthreads();
#pragma unroll 2
  for (int t = 0; t < 16; ++t) {
    const int buf = (t & 1) * 16384;
    if (t < 15) G1S((t & 1) ^ 1, t + 1);
    bf16x8 af[2][4], bg[4];
#pragma unroll
    for (int i = 0; i < 2; ++i) {
      const int r = wr + i * 16 + fr;
#pragma unroll
      for (int ks = 0; ks < 4; ++ks)
        af[i][ks] = *(const bf16x8*)&lds[buf + r * 128 + ((((ks << 2) + h) ^ (r & 15)) << 3)];
    }
    {
      const int c = wc + fr;
#pragma unroll
      for (int ks = 0; ks < 4; ++ks)
        bg[ks] = *(const bf16x8*)&lds[buf + 8192 + c * 128 + ((((ks << 2) + h) ^ (c & 15)) << 3)];
    }
#pragma unroll
    for (int ks = 0; ks < 4; ++ks)
#pragma unroll
      for (int i = 0; i < 2; ++i)
        acc[i] = __builtin_amdgcn_mfma_f32_16x16x32_bf16(af[i][ks], bg[ks], acc[i], 0, 0, 0);
    __syncthreads();
  }
#pragma unroll
  for (int i = 0; i < 2; ++i)
#pragma unroll
    for (int g = 0; g < 4; ++g) {
      int r = row0 + wr + i * 16 + h * 4 + g;
      int c = col0 + wc + fr;
      float val = acc[i][g] - Y[(size_t)r * D + c];
      if (FOUT) outf[(size_t)r * D + c] = val;
      else      outb[(size_t)r * D + c] = f2b(val);
    }
#undef G1S
}

__device__ __forceinline__ void phase_g2(u16* lds, const u16* __restrict__ Tb,
                                         const u16* __restrict__ Ab,
                                         u16* __restrict__ Gb, int bid, int tid) {
  const int lane = tid & 63, wid = tid >> 6;
  const int row0 = (bid >> 4) * 128, col0 = (bid & 15) * 128;
  const int wr = (wid >> 2) * 64, wc = (wid & 3) * 32;
  const int fr = lane & 15, h = lane >> 4;
  const int grow = lane >> 3, gslot = lane & 7;
  f32x4 acc[4][2] = {};

#define G2S(BUF, T)                                                              \
  {                                                                              \
    const int k0 = (T) * 64;                                                     \
    _Pragma("unroll") for (int q = 0; q < 2; ++q) {                              \
      const int m = wid * 2 + q;                                                 \
      const int r = m * 8 + grow;                                                \
      const int kl = (gslot ^ (r & 7)) * 8;                                      \
      gload16(&Tb[(size_t)(row0 + r) * 512 + k0 + kl], &lds[(BUF)*16384 + m*512]);         \
      gload16(&Ab[(size_t)(col0 + r) * 512 + k0 + kl], &lds[(BUF)*16384 + 8192 + m*512]);  \
    }                                                                            \
  }

  G2S(0, 0);
  __syncthreads();
#pragma unroll 2
  for (int t = 0; t < 8; ++t) {
    const int buf = (t & 1) * 16384;
    if (t < 7) G2S((t & 1) ^ 1, t + 1);
    bf16x8 af[4][2], bg[2][2];
#pragma unroll
    for (int i = 0; i < 4; ++i) {
      const int r = wr + i * 16 + fr;
#pragma unroll
      for (int ks = 0; ks < 2; ++ks)
        af[i][ks] = *(const bf16x8*)&lds[buf + r * 64 + ((((ks << 2) + h) ^ (r & 7)) << 3)];
    }
#pragma unroll
    for (int j = 0; j < 2; ++j) {
      const int c = wc + j * 16 + fr;
#pragma unroll
      for (int ks = 0; ks < 2; ++ks)
        bg[j][ks] = *(const bf16x8*)&lds[buf + 8192 + c * 64 + ((((ks << 2) + h) ^ (c & 7)) << 3)];
    }
#pragma unroll
    for (int ks = 0; ks < 2; ++ks)
#pragma unroll
      for (int i = 0; i < 4; ++i)
#pragma unroll
        for (int j = 0; j < 2; ++j)
          acc[i][j] = __builtin_amdgcn_mfma_f32_16x16x32_bf16(af[i][ks], bg[j][ks], acc[i][j], 0, 0, 0);
    __syncthreads();
  }
#pragma unroll
  for (int i = 0; i < 4; ++i)
#pragma unroll
    for (int j = 0; j < 2; ++j)
#pragma unroll
      for (int g = 0; g < 4; ++g) {
        int r = row0 + wr + i * 16 + h * 4 + g;
        int c = col0 + wc + j * 16 + fr;
        Gb[(size_t)r * N + c] = f2b(acc[i][j][g]);
      }
#undef G2S
}

__device__ __forceinline__ void phase_prox(const u16* __restrict__ Gb,
                                           u16* __restrict__ Zb, u16* __restrict__ Xb,
                                           float s2, float beta, int bid, int tid) {
  const int wid = tid >> 6, lane = tid & 63;
  const int row = bid * 8 + wid;
  const size_t rb = (size_t)row * N;
  float v[32], xo[32];
  float mn = 1e30f, mx = -1e30f;
#pragma unroll
  for (int c = 0; c < 4; ++c) {
    const int base = c * 512 + lane * 8;
    uint4 zu = *(const uint4*)&Zb[rb + base];
    uint4 gu = *(const uint4*)&Gb[rb + base];
    uint4 xu = *(const uint4*)&Xb[rb + base];
    const unsigned int zw[4] = {zu.x, zu.y, zu.z, zu.w};
    const unsigned int gw[4] = {gu.x, gu.y, gu.z, gu.w};
    const unsigned int xw[4] = {xu.x, xu.y, xu.z, xu.w};
#pragma unroll
    for (int w = 0; w < 4; ++w) {
      int e = c * 8 + w * 2;
      float v0 = b2f(zw[w]) - s2 * b2f(gw[w]);
      float v1 = __uint_as_float(zw[w] & 0xffff0000u) - s2 * __uint_as_float(gw[w] & 0xffff0000u);
      v[e] = v0; v[e + 1] = v1;
      xo[e] = b2f(xw[w]); xo[e + 1] = __uint_as_float(xw[w] & 0xffff0000u);
      mn = fminf(mn, fminf(v0, v1));
      mx = fmaxf(mx, fmaxf(v0, v1));
    }
  }
#pragma unroll
  for (int o = 32; o > 0; o >>= 1) {
    mn = fminf(mn, __shfl_xor(mn, o, 64));
    mx = fmaxf(mx, __shfl_xor(mx, o, 64));
  }
  float lo = mn - 1.0f, hi = mx;
  float mid = 0.5f * (lo + hi);
#pragma unroll 1
  for (int it = 0; it < NEWTON_ITERS; ++it) {
    float s = 0.f, cnt = 0.f;
#pragma unroll
    for (int e = 0; e < 32; ++e) {
      float d = v[e] - mid;
      s += fminf(fmaxf(d, 0.f), 1.f);
      cnt += (d > 0.f && d < 1.f) ? 1.f : 0.f;
    }
    s = wave_reduce_sum(s);
    cnt = wave_reduce_sum(cnt);
    bool gt = s > 1.0f;
    lo = gt ? mid : lo;
    hi = gt ? hi : mid;
    float prop = mid + (s - 1.0f) / fmaxf(cnt, 0.5f);
    mid = (prop > lo && prop < hi) ? prop : 0.5f * (lo + hi);
  }
  float tau = mid;
#pragma unroll
  for (int c = 0; c < 4; ++c) {
    const int base = c * 512 + lane * 8;
    unsigned int xp[4], zp[4];
#pragma unroll
    for (int q = 0; q < 8; ++q) {
      int e = c * 8 + q;
      float x = fminf(fmaxf(v[e] - tau, 0.f), 1.f);
      float zn = x + beta * (x - xo[e]);
      unsigned int xb = (unsigned int)f2b(x);
      unsigned int zb = (unsigned int)f2b(zn);
      if (q & 1) { xp[q >> 1] |= xb << 16; zp[q >> 1] |= zb << 16; }
      else       { xp[q >> 1] = xb;        zp[q >> 1] = zb; }
    }
    *(uint4*)&Xb[rb + base] = make_uint4(xp[0], xp[1], xp[2], xp[3]);
    *(uint4*)&Zb[rb + base] = make_uint4(zp[0], zp[1], zp[2], zp[3]);
  }
}

__global__ __launch_bounds__(512) void fista_kernel(const u16* __restrict__ Ab,
                                                    const u16* __restrict__ AbT,
                                                    const float* __restrict__ Y,
                                                    u16* __restrict__ Zb,
                                                    u16* __restrict__ Gb,
                                                    u16* __restrict__ Xb,
                                                    u16* __restrict__ Tb,
                                                    float* __restrict__ T32,
                                                    const float* __restrict__ sp,
                                                    unsigned int* __restrict__ bar) {
  __shared__ u16 lds[2 * 16384];  // 64 KB, shared by g1/g2 phases
  const int bid = blockIdx.x, tid = threadIdx.x;
  const float s2 = 2.0f * sp[0];
  float t = 1.0f;
  for (int it = 0; it < N_ITERS; ++it) {
    float tn = 0.5f * (1.0f + sqrtf(1.0f + 4.0f * t * t));
    float beta = (t - 1.0f) / tn;
    t = tn;
    phase_g1<0>(lds, Zb, AbT, Y, Tb, T32, bid, tid);
    grid_barrier(bar);
    phase_g2(lds, Tb, Ab, Gb, bid, tid);
    grid_barrier(bar);
    phase_prox(Gb, Zb, Xb, s2, beta, bid, tid);
    grid_barrier(bar);
  }
  // final exact objective residual from Xb (fp32 out)
  phase_g1<1>(lds, Xb, AbT, Y, Tb, T32, bid, tid);
}

// ---------------- final reduction: out = -mean(T32^2) ----------------
__global__ void zero_out_kernel(float* __restrict__ out) {
  if (threadIdx.x == 0 && blockIdx.x == 0) out[0] = 0.f;
}

__global__ __launch_bounds__(256) void mse_reduce_kernel(const float* __restrict__ T,
                                                         float* __restrict__ out) {
  size_t i = (size_t)blockIdx.x * blockDim.x + threadIdx.x;
  size_t total = (size_t)N * D;
  size_t stride = (size_t)gridDim.x * blockDim.x;
  float acc = 0.f;
  for (size_t idx = i; idx < total; idx += stride) {
    float t = T[idx];
    acc = fmaf(t, t, acc);
  }
  acc = wave_reduce_sum(acc);
  __shared__ float sred[4];
  int wid = threadIdx.x >> 6, lane = threadIdx.x & 63;
  if (lane == 0) sred[wid] = acc;
  __syncthreads();
  if (threadIdx.x == 0) {
    float tot = sred[0] + sred[1] + sred[2] + sred[3];
    atomicAdd(out, -tot / (float)((size_t)N * D));
  }
}

extern "C" void kernel_launch(void* const* d_in, const int* in_sizes, int n_in,
                              void* d_out, int out_size, void* d_ws, size_t ws_size,
                              hipStream_t stream) {
  const float* fea1 = (const float*)d_in[0];
  const float* fea2 = (const float*)d_in[1];
  float* out = (float*)d_out;
  float* ws = (float*)d_ws;

  // workspace layout (~42 MB, all 16B-aligned)
  float* A   = ws;                        // [N*D] fp32 nfea2
  float* Y   = A + (size_t)N * D;         // [N*D] fp32 nfea1
  float* T32 = Y + (size_t)N * D;         // [N*D] fp32 final residual
  float* vv  = T32 + (size_t)N * D;       // [N]
  float* wv  = vv + N;                    // [N]
  float* uu  = wv + N;                    // [D]
  float* sp  = uu + D;                    // [8] step
  unsigned int* bar = (unsigned int*)(sp + 8);  // [8] barrier state
  u16* Zb    = (u16*)(bar + 8);           // [N*N] bf16 Z
  u16* Gb    = Zb + (size_t)N * N;        // [N*N] bf16 G = T@A^T
  u16* Xb    = Gb + (size_t)N * N;        // [N*N] bf16 X
  u16* Tb    = Xb + (size_t)N * N;        // [N*D] bf16 T
  u16* Ab    = Tb + (size_t)N * D;        // [N*D] bf16 A
  u16* AbT   = Ab + (size_t)N * D;        // [D*N] bf16 A^T

  rownorm_kernel<<<2 * N, 256, 0, stream>>>(fea1, fea2, Y, A);
  prep_kernel<<<dim3(D / 32, N / 32), 256, 0, stream>>>(A, Ab, AbT);
  fill_init<<<(N * N / 8) / 256, 256, 0, stream>>>(Zb, Xb, vv, bar);

  // power iteration, unnormalized with fixed 1/16 rescale (direction-invariant)
  float* pv = vv;
  float* pw = wv;
  for (int it = 0; it < POWER_ITERS; ++it) {
    atv_kernel<<<D / 64, 256, 0, stream>>>(Ab, pv, uu);
    av_kernel<<<N / 4, 256, 0, stream>>>(Ab, uu, pw);
    float* tmp = pv; pv = pw; pw = tmp;
  }
  atv_kernel<<<D / 64, 256, 0, stream>>>(Ab, pv, uu);
  av_kernel<<<N / 4, 256, 0, stream>>>(Ab, uu, pw);
  rayleigh_kernel<<<1, 1024, 0, stream>>>(pv, pw, sp);

  // the entire 200-iteration FISTA loop in one persistent kernel
  fista_kernel<<<NBLOCKS, 512, 0, stream>>>(Ab, AbT, Y, Zb, Gb, Xb, Tb, T32, sp, bar);

  zero_out_kernel<<<1, 64, 0, stream>>>(out);
  mse_reduce_kernel<<<512, 256, 0, stream>>>(T32, out);
}

// Round 8
// 9433.292 us; speedup vs baseline: 3.2549x; 3.2549x over previous
//
#include <hip/hip_runtime.h>
#include <cmath>

#define N 2048
#define D 512
#define N_ITERS 200
#define NEWTON_ITERS 12
#define POWER_ITERS 30

typedef unsigned short u16;
typedef __bf16 bf16x8 __attribute__((ext_vector_type(8)));
typedef float f32x4 __attribute__((ext_vector_type(4)));

__device__ __forceinline__ float wave_reduce_sum(float x) {
#pragma unroll
  for (int o = 32; o > 0; o >>= 1) x += __shfl_xor(x, o, 64);
  return x;
}

__device__ __forceinline__ u16 f2b(float f) {  // fp32 -> bf16 RNE
  unsigned int u = __float_as_uint(f);
  u = (u + 0x7FFFu + ((u >> 16) & 1u)) >> 16;
  return (u16)u;
}

__device__ __forceinline__ float b2f(unsigned int lo16) {
  return __uint_as_float((lo16 & 0xffffu) << 16);
}

// async 16B global->LDS (wave-uniform LDS base + implicit lane*16; per-lane global src)
__device__ __forceinline__ void gload16(const u16* g, u16* l) {
  __builtin_amdgcn_global_load_lds(
      (const __attribute__((address_space(1))) unsigned int*)g,
      (__attribute__((address_space(3))) unsigned int*)l, 16, 0, 0);
}

// ------------- row normalization: Y/Yb = fea1/||row||, A = fea2/||row|| -------------
__global__ __launch_bounds__(256) void rownorm_kernel(const float* __restrict__ fea1,
                                                      const float* __restrict__ fea2,
                                                      float* __restrict__ Y,
                                                      u16* __restrict__ Yb,
                                                      float* __restrict__ A) {
  int b = blockIdx.x;
  int row = b & (N - 1);
  const float* src = (b < N) ? fea1 : fea2;
  float* dst = (b < N) ? Y : A;
  const float2* s2 = (const float2*)(src + (size_t)row * D);
  float2* d2 = (float2*)(dst + (size_t)row * D);
  int t = threadIdx.x;
  float2 v = s2[t];
  float ss = v.x * v.x + v.y * v.y;
  ss = wave_reduce_sum(ss);
  __shared__ float sred[4];
  int wid = t >> 6, lane = t & 63;
  if (lane == 0) sred[wid] = ss;
  __syncthreads();
  if (t == 0) sred[0] = sred[0] + sred[1] + sred[2] + sred[3];
  __syncthreads();
  float inv = 1.0f / sqrtf(sred[0]);
  float2 o = make_float2(v.x * inv, v.y * inv);
  d2[t] = o;
  if (b < N) {
    unsigned int pk = (unsigned int)f2b(o.x) | ((unsigned int)f2b(o.y) << 16);
    *(unsigned int*)&Yb[(size_t)row * D + t * 2] = pk;
  }
}

// ---------------- prep: Ab = bf16(A), AbT = bf16(A)^T ----------------
__global__ __launch_bounds__(256) void prep_kernel(const float* __restrict__ A,
                                                   u16* __restrict__ Ab,
                                                   u16* __restrict__ AbT) {
  __shared__ float tile[32][33];
  int c0 = blockIdx.x * 32, r0 = blockIdx.y * 32;
  int tid = threadIdx.x;
  int r = tid >> 3, q = tid & 7;
  float4 v = *(const float4*)&A[(size_t)(r0 + r) * D + c0 + q * 4];
  tile[r][q * 4 + 0] = v.x; tile[r][q * 4 + 1] = v.y;
  tile[r][q * 4 + 2] = v.z; tile[r][q * 4 + 3] = v.w;
  ushort4 b4 = make_ushort4(f2b(v.x), f2b(v.y), f2b(v.z), f2b(v.w));
  *(ushort4*)&Ab[(size_t)(r0 + r) * D + c0 + q * 4] = b4;
  __syncthreads();
  int c = tid >> 3, qq = tid & 7;
  ushort4 t4 = make_ushort4(f2b(tile[qq * 4 + 0][c]), f2b(tile[qq * 4 + 1][c]),
                            f2b(tile[qq * 4 + 2][c]), f2b(tile[qq * 4 + 3][c]));
  *(ushort4*)&AbT[(size_t)(c0 + c) * N + r0 + qq * 4] = t4;
}

// ---------------- init Zb = Xb = bf16(1/N) ----------------
__global__ __launch_bounds__(256) void fill_init(u16* __restrict__ Zb, u16* __restrict__ Xb) {
  const unsigned int cw = (unsigned int)f2b(1.0f / (float)N);
  const unsigned int pp = cw | (cw << 16);
  size_t i = (size_t)blockIdx.x * blockDim.x + threadIdx.x;  // 0 .. N*N/8-1
  uint4 val = make_uint4(pp, pp, pp, pp);
  ((uint4*)Zb)[i] = val;
  ((uint4*)Xb)[i] = val;
}

// ---------------- Mb = bf16( AbT @ AbT^T )  (512x512, K=2048, symmetric) ----------------
__global__ __launch_bounds__(256) void ata_kernel(const u16* __restrict__ AbT,
                                                  u16* __restrict__ Mb) {
  __shared__ float Ts[64][17];
  __shared__ float As[64][17];
  const int tid = threadIdx.x;
  const int row0 = blockIdx.y * 64, col0 = blockIdx.x * 64;
  const int tx = tid & 15, ty = tid >> 4;
  const int lr = tid >> 2;
  const int lk = (tid & 3) * 4;
  float acc[4][4] = {};
  for (int k0 = 0; k0 < N; k0 += 16) {
    ushort4 t4 = *(const ushort4*)(AbT + (size_t)(row0 + lr) * N + k0 + lk);
    ushort4 a4 = *(const ushort4*)(AbT + (size_t)(col0 + lr) * N + k0 + lk);
    Ts[lr][lk + 0] = b2f(t4.x); Ts[lr][lk + 1] = b2f(t4.y);
    Ts[lr][lk + 2] = b2f(t4.z); Ts[lr][lk + 3] = b2f(t4.w);
    As[lr][lk + 0] = b2f(a4.x); As[lr][lk + 1] = b2f(a4.y);
    As[lr][lk + 2] = b2f(a4.z); As[lr][lk + 3] = b2f(a4.w);
    __syncthreads();
#pragma unroll
    for (int kk = 0; kk < 16; ++kk) {
      float ar[4], br[4];
#pragma unroll
      for (int i = 0; i < 4; ++i) ar[i] = Ts[ty * 4 + i][kk];
#pragma unroll
      for (int j = 0; j < 4; ++j) br[j] = As[tx * 4 + j][kk];
#pragma unroll
      for (int i = 0; i < 4; ++i)
#pragma unroll
        for (int j = 0; j < 4; ++j) acc[i][j] = fmaf(ar[i], br[j], acc[i][j]);
    }
    __syncthreads();
  }
#pragma unroll
  for (int i = 0; i < 4; ++i) {
    int r = row0 + ty * 4 + i;
#pragma unroll
    for (int j = 0; j < 4; ++j) {
      int c = col0 + tx * 4 + j;
      Mb[(size_t)r * D + c] = f2b(acc[i][j]);
    }
  }
}

// ---------------- 30 power iters + Rayleigh on Mb, single block ----------------
__global__ __launch_bounds__(512) void powerM_kernel(const u16* __restrict__ Mb,
                                                     float* __restrict__ sp) {
  __shared__ float v[D];
  __shared__ float r1[8], r2[8];
  const int tid = threadIdx.x;
  v[tid] = 1.0f;
  __syncthreads();
  for (int it = 0; it < POWER_ITERS; ++it) {
    float acc = 0.f;
#pragma unroll 8
    for (int k = 0; k < D; ++k) acc = fmaf(b2f(Mb[(size_t)k * D + tid]), v[k], acc);
    __syncthreads();
    v[tid] = acc * 0.0625f;  // fixed 1/16 rescale keeps fp32 range
    __syncthreads();
  }
  float acc = 0.f;
#pragma unroll 8
  for (int k = 0; k < D; ++k) acc = fmaf(b2f(Mb[(size_t)k * D + tid]), v[k], acc);
  float vi = v[tid];
  float num = wave_reduce_sum(vi * acc);
  float den = wave_reduce_sum(vi * vi);
  int wid = tid >> 6, lane = tid & 63;
  if (lane == 0) { r1[wid] = num; r2[wid] = den; }
  __syncthreads();
  if (tid == 0) {
    float t1 = 0.f, t2 = 0.f;
#pragma unroll
    for (int i = 0; i < 8; ++i) { t1 += r1[i]; t2 += r2[i]; }
    float lam = t1 / t2;
    sp[0] = 1.0f / (2.0f * lam + 1e-12f);
  }
}

// ================= loop GEMMs: 8-wave, gload_lds + XOR-swizzle + 2-phase dbuf =========

// GEMM1: T = Zb @ A - Y.  M=2048, cols=512, K=2048. 64x64 tile, 8 waves (2x4), BK=128.
// FOUT=0: bf16 out (Tb), bf16 Yb subtract; FOUT=1: fp32 out (T32), fp32 Y subtract.
template <int FOUT>
__global__ __launch_bounds__(512) void gemm1_mfma(const u16* __restrict__ Am,
                                                  const u16* __restrict__ Bm,
                                                  const u16* __restrict__ Yb,
                                                  const float* __restrict__ Y,
                                                  u16* __restrict__ outb,
                                                  float* __restrict__ outf) {
  __shared__ u16 lds[2 * 16384];
  const int bid = blockIdx.x, tid = threadIdx.x;
  const int lane = tid & 63, wid = tid >> 6;
  const int row0 = (bid >> 3) * 64, col0 = (bid & 7) * 64;
  const int wr = (wid >> 2) * 32, wc = (wid & 3) * 16;
  const int fr = lane & 15, h = lane >> 4;
  const int grow = lane >> 4, gslot = lane & 15;
  f32x4 acc[2] = {};

#define G1S(BUF, T)                                                              \
  {                                                                              \
    const int k0 = (T) * 128;                                                    \
    _Pragma("unroll") for (int q = 0; q < 2; ++q) {                              \
      const int m = wid * 2 + q;                                                 \
      const int r = m * 4 + grow;                                                \
      const int kl = (gslot ^ (r & 15)) * 8;                                     \
      gload16(&Am[(size_t)(row0 + r) * 2048 + k0 + kl], &lds[(BUF)*16384 + m*512]);        \
      gload16(&Bm[(size_t)(col0 + r) * 2048 + k0 + kl], &lds[(BUF)*16384 + 8192 + m*512]); \
    }                                                                            \
  }

  G1S(0, 0);
  __syncthreads();
#pragma unroll 2
  for (int t = 0; t < 16; ++t) {
    const int buf = (t & 1) * 16384;
    if (t < 15) G1S((t & 1) ^ 1, t + 1);
    bf16x8 af[2][4], bg[4];
#pragma unroll
    for (int i = 0; i < 2; ++i) {
      const int r = wr + i * 16 + fr;
#pragma unroll
      for (int ks = 0; ks < 4; ++ks)
        af[i][ks] = *(const bf16x8*)&lds[buf + r * 128 + ((((ks << 2) + h) ^ (r & 15)) << 3)];
    }
    {
      const int c = wc + fr;
#pragma unroll
      for (int ks = 0; ks < 4; ++ks)
        bg[ks] = *(const bf16x8*)&lds[buf + 8192 + c * 128 + ((((ks << 2) + h) ^ (c & 15)) << 3)];
    }
#pragma unroll
    for (int ks = 0; ks < 4; ++ks)
#pragma unroll
      for (int i = 0; i < 2; ++i)
        acc[i] = __builtin_amdgcn_mfma_f32_16x16x32_bf16(af[i][ks], bg[ks], acc[i], 0, 0, 0);
    __syncthreads();
  }
#pragma unroll
  for (int i = 0; i < 2; ++i)
#pragma unroll
    for (int g = 0; g < 4; ++g) {
      int r = row0 + wr + i * 16 + h * 4 + g;
      int c = col0 + wc + fr;
      if (FOUT) outf[(size_t)r * D + c] = acc[i][g] - Y[(size_t)r * D + c];
      else      outb[(size_t)r * D + c] = f2b(acc[i][g] - b2f(Yb[(size_t)r * D + c]));
    }
#undef G1S
}

// GEMM2 fused: Vb = Zb - 2*step*(Tb @ Ab^T).  M=N=2048, K=512. 128x128 tile, 8 waves.
__global__ __launch_bounds__(512) void gemm2_mfma(const u16* __restrict__ Tb,
                                                  const u16* __restrict__ Ab,
                                                  const u16* __restrict__ Zb,
                                                  const float* __restrict__ sp,
                                                  u16* __restrict__ Vb) {
  __shared__ u16 lds[2 * 16384];
  const int bid = blockIdx.x, tid = threadIdx.x;
  const int lane = tid & 63, wid = tid >> 6;
  const int row0 = (bid >> 4) * 128, col0 = (bid & 15) * 128;
  const int wr = (wid >> 2) * 64, wc = (wid & 3) * 32;
  const int fr = lane & 15, h = lane >> 4;
  const int grow = lane >> 3, gslot = lane & 7;
  f32x4 acc[4][2] = {};

#define G2S(BUF, T)                                                              \
  {                                                                              \
    const int k0 = (T) * 64;                                                     \
    _Pragma("unroll") for (int q = 0; q < 2; ++q) {                              \
      const int m = wid * 2 + q;                                                 \
      const int r = m * 8 + grow;                                                \
      const int kl = (gslot ^ (r & 7)) * 8;                                      \
      gload16(&Tb[(size_t)(row0 + r) * 512 + k0 + kl], &lds[(BUF)*16384 + m*512]);         \
      gload16(&Ab[(size_t)(col0 + r) * 512 + k0 + kl], &lds[(BUF)*16384 + 8192 + m*512]);  \
    }                                                                            \
  }

  G2S(0, 0);
  __syncthreads();
#pragma unroll 2
  for (int t = 0; t < 8; ++t) {
    const int buf = (t & 1) * 16384;
    if (t < 7) G2S((t & 1) ^ 1, t + 1);
    bf16x8 af[4][2], bg[2][2];
#pragma unroll
    for (int i = 0; i < 4; ++i) {
      const int r = wr + i * 16 + fr;
#pragma unroll
      for (int ks = 0; ks < 2; ++ks)
        af[i][ks] = *(const bf16x8*)&lds[buf + r * 64 + ((((ks << 2) + h) ^ (r & 7)) << 3)];
    }
#pragma unroll
    for (int j = 0; j < 2; ++j) {
      const int c = wc + j * 16 + fr;
#pragma unroll
      for (int ks = 0; ks < 2; ++ks)
        bg[j][ks] = *(const bf16x8*)&lds[buf + 8192 + c * 64 + ((((ks << 2) + h) ^ (c & 7)) << 3)];
    }
#pragma unroll
    for (int ks = 0; ks < 2; ++ks)
#pragma unroll
      for (int i = 0; i < 4; ++i)
#pragma unroll
        for (int j = 0; j < 2; ++j)
          acc[i][j] = __builtin_amdgcn_mfma_f32_16x16x32_bf16(af[i][ks], bg[j][ks], acc[i][j], 0, 0, 0);
    __syncthreads();
  }
  const float s2 = 2.0f * sp[0];
#pragma unroll
  for (int i = 0; i < 4; ++i)
#pragma unroll
    for (int j = 0; j < 2; ++j)
#pragma unroll
      for (int g = 0; g < 4; ++g) {
        int r = row0 + wr + i * 16 + h * 4 + g;
        int c = col0 + wc + j * 16 + fr;
        size_t idx = (size_t)r * N + c;
        Vb[idx] = f2b(b2f(Zb[idx]) - s2 * acc[i][j][g]);
      }
#undef G2S
}

// ---- prox: capped-simplex projection of each row of Vb; momentum -> Zb, X -> Xb ----
// bracket: f(tau)=sum clamp(v-tau,0,1)-1; f(mx-1)>=0>f(mx) always -> [mx-1, mx].
__global__ __launch_bounds__(256) void prox_kernel(const u16* __restrict__ Vb,
                                                   u16* __restrict__ Zb,
                                                   u16* __restrict__ Xb,
                                                   float beta) {
  const int wid = threadIdx.x >> 6, lane = threadIdx.x & 63;
  const int row = blockIdx.x * 4 + wid;
  const size_t rb = (size_t)row * N;
  float v[32], xo[32];
  float mx = -1e30f;
#pragma unroll
  for (int c = 0; c < 4; ++c) {
    const int base = c * 512 + lane * 8;
    uint4 vu = *(const uint4*)&Vb[rb + base];
    uint4 xu = *(const uint4*)&Xb[rb + base];
    const unsigned int vw[4] = {vu.x, vu.y, vu.z, vu.w};
    const unsigned int xw[4] = {xu.x, xu.y, xu.z, xu.w};
#pragma unroll
    for (int w = 0; w < 4; ++w) {
      int e = c * 8 + w * 2;
      float v0 = b2f(vw[w]);
      float v1 = __uint_as_float(vw[w] & 0xffff0000u);
      v[e] = v0; v[e + 1] = v1;
      xo[e] = b2f(xw[w]); xo[e + 1] = __uint_as_float(xw[w] & 0xffff0000u);
      mx = fmaxf(mx, fmaxf(v0, v1));
    }
  }
#pragma unroll
  for (int o = 32; o > 0; o >>= 1) mx = fmaxf(mx, __shfl_xor(mx, o, 64));
  float lo = mx - 1.0f, hi = mx;
  float mid = mx - 0.5f;
#pragma unroll 1
  for (int it = 0; it < NEWTON_ITERS; ++it) {
    float s = 0.f, cnt = 0.f;
#pragma unroll
    for (int e = 0; e < 32; ++e) {
      float d = v[e] - mid;
      float m = __builtin_amdgcn_fmed3f(d, 0.f, 1.f);
      s += m;
      cnt += (m == d) ? 1.f : 0.f;
    }
    s = wave_reduce_sum(s);
    cnt = wave_reduce_sum(cnt);
    bool gt = s > 1.0f;
    lo = gt ? mid : lo;
    hi = gt ? hi : mid;
    float prop = mid + (s - 1.0f) / fmaxf(cnt, 0.5f);
    mid = (prop > lo && prop < hi) ? prop : 0.5f * (lo + hi);
  }
  float tau = mid;
#pragma unroll
  for (int c = 0; c < 4; ++c) {
    const int base = c * 512 + lane * 8;
    unsigned int xp[4], zp[4];
#pragma unroll
    for (int q = 0; q < 8; ++q) {
      int e = c * 8 + q;
      float x = __builtin_amdgcn_fmed3f(v[e] - tau, 0.f, 1.f);
      float zn = x + beta * (x - xo[e]);
      unsigned int xb = (unsigned int)f2b(x);
      unsigned int zb = (unsigned int)f2b(zn);
      if (q & 1) { xp[q >> 1] |= xb << 16; zp[q >> 1] |= zb << 16; }
      else       { xp[q >> 1] = xb;        zp[q >> 1] = zb; }
    }
    *(uint4*)&Xb[rb + base] = make_uint4(xp[0], xp[1], xp[2], xp[3]);
    *(uint4*)&Zb[rb + base] = make_uint4(zp[0], zp[1], zp[2], zp[3]);
  }
}

// ---------------- final reduction: out = -mean(T32^2) ----------------
__global__ void zero_out_kernel(float* __restrict__ out) {
  if (threadIdx.x == 0 && blockIdx.x == 0) out[0] = 0.f;
}

__global__ __launch_bounds__(256) void mse_reduce_kernel(const float* __restrict__ T,
                                                         float* __restrict__ out) {
  size_t i = (size_t)blockIdx.x * blockDim.x + threadIdx.x;
  size_t total = (size_t)N * D;
  size_t stride = (size_t)gridDim.x * blockDim.x;
  float acc = 0.f;
  for (size_t idx = i; idx < total; idx += stride) {
    float t = T[idx];
    acc = fmaf(t, t, acc);
  }
  acc = wave_reduce_sum(acc);
  __shared__ float sred[4];
  int wid = threadIdx.x >> 6, lane = threadIdx.x & 63;
  if (lane == 0) sred[wid] = acc;
  __syncthreads();
  if (threadIdx.x == 0) {
    float tot = sred[0] + sred[1] + sred[2] + sred[3];
    atomicAdd(out, -tot / (float)((size_t)N * D));
  }
}

extern "C" void kernel_launch(void* const* d_in, const int* in_sizes, int n_in,
                              void* d_out, int out_size, void* d_ws, size_t ws_size,
                              hipStream_t stream) {
  const float* fea1 = (const float*)d_in[0];
  const float* fea2 = (const float*)d_in[1];
  float* out = (float*)d_out;
  float* ws = (float*)d_ws;

  // workspace layout (~45 MB, all 16B-aligned)
  float* A   = ws;                        // [N*D] fp32 nfea2
  float* Y   = A + (size_t)N * D;         // [N*D] fp32 nfea1 (final objective only)
  float* T32 = Y + (size_t)N * D;         // [N*D] fp32 final residual
  float* sp  = T32 + (size_t)N * D;       // [8] step
  u16* Zb    = (u16*)(sp + 8);            // [N*N] bf16 Z
  u16* Vb    = Zb + (size_t)N * N;        // [N*N] bf16 V = Z - 2s*G
  u16* Xb    = Vb + (size_t)N * N;        // [N*N] bf16 X
  u16* Tb    = Xb + (size_t)N * N;        // [N*D] bf16 T
  u16* Ab    = Tb + (size_t)N * D;        // [N*D] bf16 A
  u16* AbT   = Ab + (size_t)N * D;        // [D*N] bf16 A^T
  u16* Yb    = AbT + (size_t)D * N;       // [N*D] bf16 Y
  u16* Mb    = Yb + (size_t)N * D;        // [D*D] bf16 M = A^T A

  rownorm_kernel<<<2 * N, 256, 0, stream>>>(fea1, fea2, Y, Yb, A);
  prep_kernel<<<dim3(D / 32, N / 32), 256, 0, stream>>>(A, Ab, AbT);
  fill_init<<<(N * N / 8) / 256, 256, 0, stream>>>(Zb, Xb);

  // Lipschitz: lmax(A A^T) = lmax(A^T A) via 512x512 M, 30 power iters in one block
  ata_kernel<<<dim3(D / 64, D / 64), 256, 0, stream>>>(AbT, Mb);
  powerM_kernel<<<1, 512, 0, stream>>>(Mb, sp);

  float t = 1.0f;
  for (int it = 0; it < N_ITERS; ++it) {
    float tn = 0.5f * (1.0f + sqrtf(1.0f + 4.0f * t * t));
    float beta = (t - 1.0f) / tn;
    t = tn;
    gemm1_mfma<0><<<256, 512, 0, stream>>>(Zb, AbT, Yb, Y, Tb, T32);
    gemm2_mfma<<<256, 512, 0, stream>>>(Tb, Ab, Zb, sp, Vb);
    prox_kernel<<<N / 4, 256, 0, stream>>>(Vb, Zb, Xb, beta);
  }

  // final exact objective residual from Xb (fp32 out, fp32 Y)
  gemm1_mfma<1><<<256, 512, 0, stream>>>(Xb, AbT, Yb, Y, Tb, T32);
  zero_out_kernel<<<1, 64, 0, stream>>>(out);
  mse_reduce_kernel<<<512, 256, 0, stream>>>(T32, out);
}

// Round 12
// 9280.579 us; speedup vs baseline: 3.3085x; 1.0165x over previous
//
#include <hip/hip_runtime.h>
#include <cmath>

#define N 2048
#define D 512
#define N_ITERS 200
#define NEWTON_ITERS 12
#define POWER_ITERS 30

typedef unsigned short u16;
typedef __bf16 bf16x8 __attribute__((ext_vector_type(8)));
typedef float f32x4 __attribute__((ext_vector_type(4)));

__device__ __forceinline__ float wave_reduce_sum(float x) {
#pragma unroll
  for (int o = 32; o > 0; o >>= 1) x += __shfl_xor(x, o, 64);
  return x;
}

__device__ __forceinline__ u16 f2b(float f) {  // fp32 -> bf16 RNE
  unsigned int u = __float_as_uint(f);
  u = (u + 0x7FFFu + ((u >> 16) & 1u)) >> 16;
  return (u16)u;
}

__device__ __forceinline__ float b2f(unsigned int lo16) {
  return __uint_as_float((lo16 & 0xffffu) << 16);
}

// async 16B global->LDS (wave-uniform LDS base + implicit lane*16; per-lane global src)
__device__ __forceinline__ void gload16(const u16* g, u16* l) {
  __builtin_amdgcn_global_load_lds(
      (const __attribute__((address_space(1))) unsigned int*)g,
      (__attribute__((address_space(3))) unsigned int*)l, 16, 0, 0);
}

// XCD-chunked bijective swizzle for grid=256 on 8 XCDs (bid%8 = XCD): XCD x gets
// contiguous work chunk [x*32, x*32+32) -> same-row tiles share one XCD's L2.
__device__ __forceinline__ int xcd_swz(int bid) { return (bid & 7) * 32 + (bid >> 3); }

// ------------- row normalization: Y/Yb = fea1/||row||, A = fea2/||row|| -------------
__global__ __launch_bounds__(256) void rownorm_kernel(const float* __restrict__ fea1,
                                                      const float* __restrict__ fea2,
                                                      float* __restrict__ Y,
                                                      u16* __restrict__ Yb,
                                                      float* __restrict__ A) {
  int b = blockIdx.x;
  int row = b & (N - 1);
  const float* src = (b < N) ? fea1 : fea2;
  float* dst = (b < N) ? Y : A;
  const float2* s2 = (const float2*)(src + (size_t)row * D);
  float2* d2 = (float2*)(dst + (size_t)row * D);
  int t = threadIdx.x;
  float2 v = s2[t];
  float ss = v.x * v.x + v.y * v.y;
  ss = wave_reduce_sum(ss);
  __shared__ float sred[4];
  int wid = t >> 6, lane = t & 63;
  if (lane == 0) sred[wid] = ss;
  __syncthreads();
  if (t == 0) sred[0] = sred[0] + sred[1] + sred[2] + sred[3];
  __syncthreads();
  float inv = 1.0f / sqrtf(sred[0]);
  float2 o = make_float2(v.x * inv, v.y * inv);
  d2[t] = o;
  if (b < N) {
    unsigned int pk = (unsigned int)f2b(o.x) | ((unsigned int)f2b(o.y) << 16);
    *(unsigned int*)&Yb[(size_t)row * D + t * 2] = pk;
  }
}

// ---------------- prep: Ab = bf16(A), AbT = bf16(A)^T ----------------
__global__ __launch_bounds__(256) void prep_kernel(const float* __restrict__ A,
                                                   u16* __restrict__ Ab,
                                                   u16* __restrict__ AbT) {
  __shared__ float tile[32][33];
  int c0 = blockIdx.x * 32, r0 = blockIdx.y * 32;
  int tid = threadIdx.x;
  int r = tid >> 3, q = tid & 7;
  float4 v = *(const float4*)&A[(size_t)(r0 + r) * D + c0 + q * 4];
  tile[r][q * 4 + 0] = v.x; tile[r][q * 4 + 1] = v.y;
  tile[r][q * 4 + 2] = v.z; tile[r][q * 4 + 3] = v.w;
  ushort4 b4 = make_ushort4(f2b(v.x), f2b(v.y), f2b(v.z), f2b(v.w));
  *(ushort4*)&Ab[(size_t)(r0 + r) * D + c0 + q * 4] = b4;
  __syncthreads();
  int c = tid >> 3, qq = tid & 7;
  ushort4 t4 = make_ushort4(f2b(tile[qq * 4 + 0][c]), f2b(tile[qq * 4 + 1][c]),
                            f2b(tile[qq * 4 + 2][c]), f2b(tile[qq * 4 + 3][c]));
  *(ushort4*)&AbT[(size_t)(c0 + c) * N + r0 + qq * 4] = t4;
}

// ---------------- init Zb = Xb = bf16(1/N) ----------------
__global__ __launch_bounds__(256) void fill_init(u16* __restrict__ Zb, u16* __restrict__ Xb) {
  const unsigned int cw = (unsigned int)f2b(1.0f / (float)N);
  const unsigned int pp = cw | (cw << 16);
  size_t i = (size_t)blockIdx.x * blockDim.x + threadIdx.x;  // 0 .. N*N/8-1
  uint4 val = make_uint4(pp, pp, pp, pp);
  ((uint4*)Zb)[i] = val;
  ((uint4*)Xb)[i] = val;
}

// ---------------- Mb = bf16( AbT @ AbT^T )  (512x512, K=2048, symmetric) ----------------
__global__ __launch_bounds__(256) void ata_kernel(const u16* __restrict__ AbT,
                                                  u16* __restrict__ Mb) {
  __shared__ float Ts[64][17];
  __shared__ float As[64][17];
  const int tid = threadIdx.x;
  const int row0 = blockIdx.y * 64, col0 = blockIdx.x * 64;
  const int tx = tid & 15, ty = tid >> 4;
  const int lr = tid >> 2;
  const int lk = (tid & 3) * 4;
  float acc[4][4] = {};
  for (int k0 = 0; k0 < N; k0 += 16) {
    ushort4 t4 = *(const ushort4*)(AbT + (size_t)(row0 + lr) * N + k0 + lk);
    ushort4 a4 = *(const ushort4*)(AbT + (size_t)(col0 + lr) * N + k0 + lk);
    Ts[lr][lk + 0] = b2f(t4.x); Ts[lr][lk + 1] = b2f(t4.y);
    Ts[lr][lk + 2] = b2f(t4.z); Ts[lr][lk + 3] = b2f(t4.w);
    As[lr][lk + 0] = b2f(a4.x); As[lr][lk + 1] = b2f(a4.y);
    As[lr][lk + 2] = b2f(a4.z); As[lr][lk + 3] = b2f(a4.w);
    __syncthreads();
#pragma unroll
    for (int kk = 0; kk < 16; ++kk) {
      float ar[4], br[4];
#pragma unroll
      for (int i = 0; i < 4; ++i) ar[i] = Ts[ty * 4 + i][kk];
#pragma unroll
      for (int j = 0; j < 4; ++j) br[j] = As[tx * 4 + j][kk];
#pragma unroll
      for (int i = 0; i < 4; ++i)
#pragma unroll
        for (int j = 0; j < 4; ++j) acc[i][j] = fmaf(ar[i], br[j], acc[i][j]);
    }
    __syncthreads();
  }
#pragma unroll
  for (int i = 0; i < 4; ++i) {
    int r = row0 + ty * 4 + i;
#pragma unroll
    for (int j = 0; j < 4; ++j) {
      int c = col0 + tx * 4 + j;
      Mb[(size_t)r * D + c] = f2b(acc[i][j]);
    }
  }
}

// ---------------- 30 power iters + Rayleigh on Mb, single block ----------------
__global__ __launch_bounds__(512) void powerM_kernel(const u16* __restrict__ Mb,
                                                     float* __restrict__ sp) {
  __shared__ float v[D];
  __shared__ float r1[8], r2[8];
  const int tid = threadIdx.x;
  v[tid] = 1.0f;
  __syncthreads();
  for (int it = 0; it < POWER_ITERS; ++it) {
    float acc = 0.f;
#pragma unroll 8
    for (int k = 0; k < D; ++k) acc = fmaf(b2f(Mb[(size_t)k * D + tid]), v[k], acc);
    __syncthreads();
    v[tid] = acc * 0.0625f;  // fixed 1/16 rescale keeps fp32 range
    __syncthreads();
  }
  float acc = 0.f;
#pragma unroll 8
  for (int k = 0; k < D; ++k) acc = fmaf(b2f(Mb[(size_t)k * D + tid]), v[k], acc);
  float vi = v[tid];
  float num = wave_reduce_sum(vi * acc);
  float den = wave_reduce_sum(vi * vi);
  int wid = tid >> 6, lane = tid & 63;
  if (lane == 0) { r1[wid] = num; r2[wid] = den; }
  __syncthreads();
  if (tid == 0) {
    float t1 = 0.f, t2 = 0.f;
#pragma unroll
    for (int i = 0; i < 8; ++i) { t1 += r1[i]; t2 += r2[i]; }
    float lam = t1 / t2;
    sp[0] = 1.0f / (2.0f * lam + 1e-12f);
  }
}

// ======== loop GEMMs: 4 waves, BIG wave-tiles (LDS-read-bound fix), dbuf, swizzle ======

// GEMM1: T = Zb @ A - Y.  M=2048, cols=512, K=2048. 64x64 tile, 4 waves (2x2),
// wave-tile 32x32, BK=128 (16 steps). 16 ds_read_b128 : 16 MFMA per wave-step.
// FOUT=0: bf16 out (Tb), bf16 Yb subtract; FOUT=1: fp32 out (T32), fp32 Y subtract.
template <int FOUT>
__global__ __launch_bounds__(256) void gemm1_mfma(const u16* __restrict__ Am,
                                                  const u16* __restrict__ Bm,
                                                  const u16* __restrict__ Yb,
                                                  const float* __restrict__ Y,
                                                  u16* __restrict__ outb,
                                                  float* __restrict__ outf) {
  __shared__ u16 lds[2 * 16384];
  const int work = xcd_swz(blockIdx.x), tid = threadIdx.x;
  const int lane = tid & 63, wid = tid >> 6;
  const int row0 = (work >> 3) * 64, col0 = (work & 7) * 64;
  const int wr = (wid >> 1) * 32, wc = (wid & 1) * 32;
  const int fr = lane & 15, h = lane >> 4;
  const int grow = lane >> 4, gslot = lane & 15;
  f32x4 acc[2][2] = {};

#define G1S(BUF, T)                                                              \
  {                                                                              \
    const int k0 = (T) * 128;                                                    \
    _Pragma("unroll") for (int q = 0; q < 4; ++q) {                              \
      const int m = wid * 4 + q;                                                 \
      const int r = m * 4 + grow;                                                \
      const int kl = (gslot ^ (r & 15)) * 8;                                     \
      gload16(&Am[(size_t)(row0 + r) * 2048 + k0 + kl], &lds[(BUF)*16384 + m*512]);        \
      gload16(&Bm[(size_t)(col0 + r) * 2048 + k0 + kl], &lds[(BUF)*16384 + 8192 + m*512]); \
    }                                                                            \
  }

  G1S(0, 0);
  __syncthreads();
#pragma unroll 2
  for (int t = 0; t < 16; ++t) {
    const int buf = (t & 1) * 16384;
    if (t < 15) G1S((t & 1) ^ 1, t + 1);
    bf16x8 af[2][4], bg[2][4];
#pragma unroll
    for (int i = 0; i < 2; ++i) {
      const int r = wr + i * 16 + fr;
#pragma unroll
      for (int ks = 0; ks < 4; ++ks)
        af[i][ks] = *(const bf16x8*)&lds[buf + r * 128 + ((((ks << 2) + h) ^ (r & 15)) << 3)];
    }
#pragma unroll
    for (int j = 0; j < 2; ++j) {
      const int c = wc + j * 16 + fr;
#pragma unroll
      for (int ks = 0; ks < 4; ++ks)
        bg[j][ks] = *(const bf16x8*)&lds[buf + 8192 + c * 128 + ((((ks << 2) + h) ^ (c & 15)) << 3)];
    }
#pragma unroll
    for (int ks = 0; ks < 4; ++ks)
#pragma unroll
      for (int i = 0; i < 2; ++i)
#pragma unroll
        for (int j = 0; j < 2; ++j)
          acc[i][j] = __builtin_amdgcn_mfma_f32_16x16x32_bf16(af[i][ks], bg[j][ks], acc[i][j], 0, 0, 0);
    __syncthreads();
  }
#pragma unroll
  for (int i = 0; i < 2; ++i)
#pragma unroll
    for (int j = 0; j < 2; ++j)
#pragma unroll
      for (int g = 0; g < 4; ++g) {
        int r = row0 + wr + i * 16 + h * 4 + g;
        int c = col0 + wc + j * 16 + fr;
        if (FOUT) outf[(size_t)r * D + c] = acc[i][j][g] - Y[(size_t)r * D + c];
        else      outb[(size_t)r * D + c] = f2b(acc[i][j][g] - b2f(Yb[(size_t)r * D + c]));
      }
#undef G1S
}

// GEMM2 fused: Vb = Zb - 2*step*(Tb @ Ab^T).  M=N=2048, K=512. 128x128 tile,
// 4 waves (2x2), wave-tile 64x64, BK=64 (8 steps). 16 reads : 32 MFMA per wave-step.
__global__ __launch_bounds__(256) void gemm2_mfma(const u16* __restrict__ Tb,
                                                  const u16* __restrict__ Ab,
                                                  const u16* __restrict__ Zb,
                                                  const float* __restrict__ sp,
                                                  u16* __restrict__ Vb) {
  __shared__ u16 lds[2 * 16384];
  const int work = xcd_swz(blockIdx.x), tid = threadIdx.x;
  const int lane = tid & 63, wid = tid >> 6;
  const int row0 = (work >> 4) * 128, col0 = (work & 15) * 128;
  const int wr = (wid >> 1) * 64, wc = (wid & 1) * 64;
  const int fr = lane & 15, h = lane >> 4;
  const int grow = lane >> 3, gslot = lane & 7;
  f32x4 acc[4][4] = {};

#define G2S(BUF, T)                                                              \
  {                                                                              \
    const int k0 = (T) * 64;                                                     \
    _Pragma("unroll") for (int q = 0; q < 4; ++q) {                              \
      const int m = wid * 4 + q;                                                 \
      const int r = m * 8 + grow;                                                \
      const int kl = (gslot ^ (r & 7)) * 8;                                      \
      gload16(&Tb[(size_t)(row0 + r) * 512 + k0 + kl], &lds[(BUF)*16384 + m*512]);         \
      gload16(&Ab[(size_t)(col0 + r) * 512 + k0 + kl], &lds[(BUF)*16384 + 8192 + m*512]);  \
    }                                                                            \
  }

  G2S(0, 0);
  __syncthreads();
#pragma unroll 2
  for (int t = 0; t < 8; ++t) {
    const int buf = (t & 1) * 16384;
    if (t < 7) G2S((t & 1) ^ 1, t + 1);
    bf16x8 af[4][2], bg[4][2];
#pragma unroll
    for (int i = 0; i < 4; ++i) {
      const int r = wr + i * 16 + fr;
#pragma unroll
      for (int ks = 0; ks < 2; ++ks)
        af[i][ks] = *(const bf16x8*)&lds[buf + r * 64 + ((((ks << 2) + h) ^ (r & 7)) << 3)];
    }
#pragma unroll
    for (int j = 0; j < 4; ++j) {
      const int c = wc + j * 16 + fr;
#pragma unroll
      for (int ks = 0; ks < 2; ++ks)
        bg[j][ks] = *(const bf16x8*)&lds[buf + 8192 + c * 64 + ((((ks << 2) + h) ^ (c & 7)) << 3)];
    }
#pragma unroll
    for (int ks = 0; ks < 2; ++ks)
#pragma unroll
      for (int i = 0; i < 4; ++i)
#pragma unroll
        for (int j = 0; j < 4; ++j)
          acc[i][j] = __builtin_amdgcn_mfma_f32_16x16x32_bf16(af[i][ks], bg[j][ks], acc[i][j], 0, 0, 0);
    __syncthreads();
  }
  const float s2 = 2.0f * sp[0];
#pragma unroll
  for (int i = 0; i < 4; ++i)
#pragma unroll
    for (int j = 0; j < 4; ++j)
#pragma unroll
      for (int g = 0; g < 4; ++g) {
        int r = row0 + wr + i * 16 + h * 4 + g;
        int c = col0 + wc + j * 16 + fr;
        size_t idx = (size_t)r * N + c;
        Vb[idx] = f2b(b2f(Zb[idx]) - s2 * acc[i][j][g]);
      }
#undef G2S
}

// ---- prox: capped-simplex projection of each row of Vb; momentum -> Zb, X -> Xb ----
// bracket: f(tau)=sum clamp(v-tau,0,1)-1; f(mx-1)>=0>f(mx) always -> [mx-1, mx].
__global__ __launch_bounds__(256) void prox_kernel(const u16* __restrict__ Vb,
                                                   u16* __restrict__ Zb,
                                                   u16* __restrict__ Xb,
                                                   float beta) {
  const int wid = threadIdx.x >> 6, lane = threadIdx.x & 63;
  const int row = blockIdx.x * 4 + wid;
  const size_t rb = (size_t)row * N;
  float v[32], xo[32];
  float mx = -1e30f;
#pragma unroll
  for (int c = 0; c < 4; ++c) {
    const int base = c * 512 + lane * 8;
    uint4 vu = *(const uint4*)&Vb[rb + base];
    uint4 xu = *(const uint4*)&Xb[rb + base];
    const unsigned int vw[4] = {vu.x, vu.y, vu.z, vu.w};
    const unsigned int xw[4] = {xu.x, xu.y, xu.z, xu.w};
#pragma unroll
    for (int w = 0; w < 4; ++w) {
      int e = c * 8 + w * 2;
      float v0 = b2f(vw[w]);
      float v1 = __uint_as_float(vw[w] & 0xffff0000u);
      v[e] = v0; v[e + 1] = v1;
      xo[e] = b2f(xw[w]); xo[e + 1] = __uint_as_float(xw[w] & 0xffff0000u);
      mx = fmaxf(mx, fmaxf(v0, v1));
    }
  }
#pragma unroll
  for (int o = 32; o > 0; o >>= 1) mx = fmaxf(mx, __shfl_xor(mx, o, 64));
  float lo = mx - 1.0f, hi = mx;
  float mid = mx - 0.5f;
#pragma unroll 1
  for (int it = 0; it < NEWTON_ITERS; ++it) {
    float s = 0.f, cnt = 0.f;
#pragma unroll
    for (int e = 0; e < 32; ++e) {
      float d = v[e] - mid;
      float m = __builtin_amdgcn_fmed3f(d, 0.f, 1.f);
      s += m;
      cnt += (m == d) ? 1.f : 0.f;
    }
    s = wave_reduce_sum(s);
    cnt = wave_reduce_sum(cnt);
    bool gt = s > 1.0f;
    lo = gt ? mid : lo;
    hi = gt ? hi : mid;
    float prop = mid + (s - 1.0f) / fmaxf(cnt, 0.5f);
    mid = (prop > lo && prop < hi) ? prop : 0.5f * (lo + hi);
  }
  float tau = mid;
#pragma unroll
  for (int c = 0; c < 4; ++c) {
    const int base = c * 512 + lane * 8;
    unsigned int xp[4], zp[4];
#pragma unroll
    for (int q = 0; q < 8; ++q) {
      int e = c * 8 + q;
      float x = __builtin_amdgcn_fmed3f(v[e] - tau, 0.f, 1.f);
      float zn = x + beta * (x - xo[e]);
      unsigned int xb = (unsigned int)f2b(x);
      unsigned int zb = (unsigned int)f2b(zn);
      if (q & 1) { xp[q >> 1] |= xb << 16; zp[q >> 1] |= zb << 16; }
      else       { xp[q >> 1] = xb;        zp[q >> 1] = zb; }
    }
    *(uint4*)&Xb[rb + base] = make_uint4(xp[0], xp[1], xp[2], xp[3]);
    *(uint4*)&Zb[rb + base] = make_uint4(zp[0], zp[1], zp[2], zp[3]);
  }
}

// ---------------- final reduction: out = -mean(T32^2) ----------------
__global__ void zero_out_kernel(float* __restrict__ out) {
  if (threadIdx.x == 0 && blockIdx.x == 0) out[0] = 0.f;
}

__global__ __launch_bounds__(256) void mse_reduce_kernel(const float* __restrict__ T,
                                                         float* __restrict__ out) {
  size_t i = (size_t)blockIdx.x * blockDim.x + threadIdx.x;
  size_t total = (size_t)N * D;
  size_t stride = (size_t)gridDim.x * blockDim.x;
  float acc = 0.f;
  for (size_t idx = i; idx < total; idx += stride) {
    float t = T[idx];
    acc = fmaf(t, t, acc);
  }
  acc = wave_reduce_sum(acc);
  __shared__ float sred[4];
  int wid = threadIdx.x >> 6, lane = threadIdx.x & 63;
  if (lane == 0) sred[wid] = acc;
  __syncthreads();
  if (threadIdx.x == 0) {
    float tot = sred[0] + sred[1] + sred[2] + sred[3];
    atomicAdd(out, -tot / (float)((size_t)N * D));
  }
}

extern "C" void kernel_launch(void* const* d_in, const int* in_sizes, int n_in,
                              void* d_out, int out_size, void* d_ws, size_t ws_size,
                              hipStream_t stream) {
  const float* fea1 = (const float*)d_in[0];
  const float* fea2 = (const float*)d_in[1];
  float* out = (float*)d_out;
  float* ws = (float*)d_ws;

  // workspace layout (~45 MB, all 16B-aligned)
  float* A   = ws;                        // [N*D] fp32 nfea2
  float* Y   = A + (size_t)N * D;         // [N*D] fp32 nfea1 (final objective only)
  float* T32 = Y + (size_t)N * D;         // [N*D] fp32 final residual
  float* sp  = T32 + (size_t)N * D;       // [8] step
  u16* Zb    = (u16*)(sp + 8);            // [N*N] bf16 Z
  u16* Vb    = Zb + (size_t)N * N;        // [N*N] bf16 V = Z - 2s*G
  u16* Xb    = Vb + (size_t)N * N;        // [N*N] bf16 X
  u16* Tb    = Xb + (size_t)N * N;        // [N*D] bf16 T
  u16* Ab    = Tb + (size_t)N * D;        // [N*D] bf16 A
  u16* AbT   = Ab + (size_t)N * D;        // [D*N] bf16 A^T
  u16* Yb    = AbT + (size_t)D * N;       // [N*D] bf16 Y
  u16* Mb    = Yb + (size_t)N * D;        // [D*D] bf16 M = A^T A

  rownorm_kernel<<<2 * N, 256, 0, stream>>>(fea1, fea2, Y, Yb, A);
  prep_kernel<<<dim3(D / 32, N / 32), 256, 0, stream>>>(A, Ab, AbT);
  fill_init<<<(N * N / 8) / 256, 256, 0, stream>>>(Zb, Xb);

  // Lipschitz: lmax(A A^T) = lmax(A^T A) via 512x512 M, 30 power iters in one block
  ata_kernel<<<dim3(D / 64, D / 64), 256, 0, stream>>>(AbT, Mb);
  powerM_kernel<<<1, 512, 0, stream>>>(Mb, sp);

  float t = 1.0f;
  for (int it = 0; it < N_ITERS; ++it) {
    float tn = 0.5f * (1.0f + sqrtf(1.0f + 4.0f * t * t));
    float beta = (t - 1.0f) / tn;
    t = tn;
    gemm1_mfma<0><<<256, 256, 0, stream>>>(Zb, AbT, Yb, Y, Tb, T32);
    gemm2_mfma<<<256, 256, 0, stream>>>(Tb, Ab, Zb, sp, Vb);
    prox_kernel<<<N / 4, 256, 0, stream>>>(Vb, Zb, Xb, beta);
  }

  // final exact objective residual from Xb (fp32 out, fp32 Y)
  gemm1_mfma<1><<<256, 256, 0, stream>>>(Xb, AbT, Yb, Y, Tb, T32);
  zero_out_kernel<<<1, 64, 0, stream>>>(out);
  mse_reduce_kernel<<<512, 256, 0, stream>>>(T32, out);
}